// Round 7
// baseline (361.696 us; speedup 1.0000x reference)
//
#include <hip/hip_runtime.h>
#include <stdint.h>

typedef unsigned short u16;
typedef unsigned int u32;
typedef __attribute__((ext_vector_type(8))) short bf16x8;
typedef __attribute__((ext_vector_type(4))) float f32x4;

#define S_LEN 4032
#define S_PAD 4096
#define DIMC  1536
#define HD    128
#define FRAME 448

static const size_t OFF_FLAG  = 0;
static const size_t OFF_CANON = 256;
static const size_t OFF_XB    = 524288;
static const size_t OFF_WT    = OFF_XB  + 12582912;
static const size_t OFF_WOT   = OFF_WT  + 14155776;
static const size_t OFF_YQ    = OFF_WOT + 4718592;
static const size_t OFF_YK    = OFF_YQ  + 12582912;
static const size_t OFF_VT    = OFF_YK  + 12582912;
static const size_t OFF_QH    = OFF_VT  + 12582912;
static const size_t OFF_KH    = OFF_QH  + 12386304;
static const size_t OFF_AT    = OFF_KH  + 12386304;
static const size_t WS_NEED   = OFF_AT  + 12582912;

#define C_BQ 0
#define C_BO 4608
#define C_GQ 6144
#define C_GK 7680
#define C_FR 9216
#define C_TOT 74752

__device__ __forceinline__ u16 f2bf(float f) {
  union { float f; u32 u; } v; v.f = f;
  u32 u = v.u;
  u32 r = (u + 0x7fffu + ((u >> 16) & 1u)) >> 16;
  return (u16)r;
}
__device__ __forceinline__ float bf2f(u16 h) {
  union { float f; u32 u; } v; v.u = ((u32)h) << 16;
  return v.f;
}

__device__ __forceinline__ void gld_lds16(const void* g, void* l) {
  __builtin_amdgcn_global_load_lds(
      (const __attribute__((address_space(1))) void*)(uintptr_t)g,
      (__attribute__((address_space(3))) void*)(u32)(uintptr_t)l,
      16, 0, 0);
}

__device__ __forceinline__ f32x4 mfma16(bf16x8 a, bf16x8 b, f32x4 c) {
  return __builtin_amdgcn_mfma_f32_16x16x32_bf16(a, b, c, 0, 0, 0);
}

// ---------------- dtype detection ----------------
__global__ void detect_dtype(const u16* __restrict__ x, int* __restrict__ flag) {
  __shared__ int cnt;
  if (threadIdx.x == 0) cnt = 0;
  __syncthreads();
  int e = (x[2 * threadIdx.x] >> 7) & 0xff;
  if (e > 150) atomicAdd(&cnt, 1);
  __syncthreads();
  if (threadIdx.x == 0) *flag = (cnt >= 8) ? 1 : 0;
}

// ---------------- small tensors -> canonical fp32 ----------------
__global__ void prep_small(const void* bq, const void* bk, const void* bv, const void* bo,
                           const void* gq, const void* gk, const void* fr,
                           float* __restrict__ canon, const int* __restrict__ flagp) {
  int fl = *flagp;
  for (int i = blockIdx.x * 256 + threadIdx.x; i < C_TOT; i += gridDim.x * 256) {
    const void* src; int j;
    if      (i < 1536) { src = bq; j = i; }
    else if (i < 3072) { src = bk; j = i - 1536; }
    else if (i < 4608) { src = bv; j = i - 3072; }
    else if (i < 6144) { src = bo; j = i - 4608; }
    else if (i < 7680) { src = gq; j = i - 6144; }
    else if (i < 9216) { src = gk; j = i - 7680; }
    else               { src = fr; j = i - 9216; }
    canon[i] = fl ? ((const float*)src)[j] : bf2f(((const u16*)src)[j]);
  }
}

// ---------------- x -> bf16, pad rows to 4096 ----------------
__global__ void convert_x(const void* __restrict__ xin, u16* __restrict__ xb,
                          const int* __restrict__ flagp) {
  int fl = *flagp;
  int i = blockIdx.x * 256 + threadIdx.x;
  if (i >= (S_PAD * DIMC) / 8) return;
  size_t base = (size_t)i * 8;
  int row = (int)(base / DIMC);
  union { u16 h[8]; uint4 v; } u;
  if (row < S_LEN) {
    if (fl) {
      const float* xf = (const float*)xin + base;
      #pragma unroll
      for (int j = 0; j < 8; j++) u.h[j] = f2bf(xf[j]);
    } else {
      const u16* xh = (const u16*)xin + base;
      #pragma unroll
      for (int j = 0; j < 8; j++) u.h[j] = xh[j];
    }
  } else {
    #pragma unroll
    for (int j = 0; j < 8; j++) u.h[j] = 0;
  }
  ((uint4*)xb)[i] = u.v;
}

// ---------------- W (K x N) -> Wt (N x K) bf16 ----------------
__global__ void transpose_w(const void* Wq, const void* Wk, const void* Wv, const void* Wo,
                            u16* __restrict__ wqkvt, u16* __restrict__ wot,
                            const int* __restrict__ flagp) {
  int fl = *flagp;
  int z = blockIdx.z;
  const void* W = (z == 0) ? Wq : (z == 1) ? Wk : (z == 2) ? Wv : Wo;
  u16* dst = (z < 3) ? (wqkvt + (size_t)z * DIMC * DIMC) : wot;
  __shared__ float tile[32][33];
  int tx = threadIdx.x, ty = threadIdx.y;
  int c = blockIdx.x * 32 + tx;
  #pragma unroll
  for (int i = 0; i < 4; i++) {
    int r = blockIdx.y * 32 + ty + i * 8;
    float v = fl ? ((const float*)W)[(size_t)r * DIMC + c]
                 : bf2f(((const u16*)W)[(size_t)r * DIMC + c]);
    tile[ty + i * 8][tx] = v;
  }
  __syncthreads();
  int k = blockIdx.y * 32 + tx;
  #pragma unroll
  for (int i = 0; i < 4; i++) {
    int n = blockIdx.x * 32 + ty + i * 8;
    dst[(size_t)n * DIMC + k] = f2bf(tile[tx][ty + i * 8]);
  }
}

// ---------------- GEMM: C(MxN) = A(MxK) @ Bt(NxK)^T + bias ----------------
// R5 grid order (n-fast 2D) + R6 zero-conflict XOR swizzle + 4 blocks/CU.
template <int MODE>
__launch_bounds__(256, 4)
__global__ void gemm_bt(const u16* __restrict__ A, const u16* __restrict__ Bt,
                        const float* __restrict__ canon,
                        u16* __restrict__ Yq, u16* __restrict__ Yk, u16* __restrict__ Vt,
                        void* __restrict__ Out, const int* __restrict__ flagp) {
  const int bm0 = blockIdx.y * 128, bn0 = blockIdx.x * 128;
  const int tid = threadIdx.x, wave = tid >> 6, lane = tid & 63;
  const int wm = wave >> 1, wn = wave & 1;
  const int l15 = lane & 15, l4 = lane >> 4;
  __shared__ u16 sA[128 * 64];
  __shared__ u16 sB[128 * 64];
  f32x4 acc[4][4];
  #pragma unroll
  for (int i = 0; i < 4; i++)
    #pragma unroll
    for (int j = 0; j < 4; j++) acc[i][j] = (f32x4){0.f, 0.f, 0.f, 0.f};

  const int swc = ((lane & 7) ^ (lane >> 3)) * 8;
  const u16* Ab = A  + (size_t)(bm0 + (lane >> 3)) * DIMC + swc;
  const u16* Bb = Bt + (size_t)(bn0 + (lane >> 3)) * DIMC + swc;

  for (int kt = 0; kt < DIMC; kt += 64) {
    __syncthreads();
    #pragma unroll
    for (int c = 0; c < 4; c++) {
      int g = wave * 4 + c;
      gld_lds16(Ab + (size_t)g * 8 * DIMC + kt, (char*)sA + g * 1024);
      gld_lds16(Bb + (size_t)g * 8 * DIMC + kt, (char*)sB + g * 1024);
    }
    __syncthreads();
    #pragma unroll
    for (int ks = 0; ks < 2; ks++) {
      bf16x8 av[4], bvv[4];
      #pragma unroll
      for (int mt = 0; mt < 4; mt++)
        av[mt]  = *(const bf16x8*)(sA + (wm * 64 + mt * 16 + l15) * 64 +
                                   (((ks * 4 + l4) ^ (l15 & 7)) * 8));
      #pragma unroll
      for (int nt = 0; nt < 4; nt++)
        bvv[nt] = *(const bf16x8*)(sB + (wn * 64 + nt * 16 + l15) * 64 +
                                   (((ks * 4 + l4) ^ (l15 & 7)) * 8));
      #pragma unroll
      for (int mt = 0; mt < 4; mt++)
        #pragma unroll
        for (int nt = 0; nt < 4; nt++)
          acc[mt][nt] = mfma16(av[mt], bvv[nt], acc[mt][nt]);
    }
  }

  const int gm0 = bm0 + wm * 64;
  const int gn0 = bn0 + wn * 64;
  if (MODE == 0) {
    #pragma unroll
    for (int nt = 0; nt < 4; nt++) {
      int gn = gn0 + nt * 16 + l15;
      float b = canon[C_BQ + gn];
      #pragma unroll
      for (int mt = 0; mt < 4; mt++) {
        int gm = gm0 + mt * 16 + l4 * 4;
        if (gn < 1536) {
          #pragma unroll
          for (int r = 0; r < 4; r++)
            Yq[(size_t)(gm + r) * DIMC + gn] = f2bf(acc[mt][nt][r] + b);
        } else if (gn < 3072) {
          int g2 = gn - 1536;
          #pragma unroll
          for (int r = 0; r < 4; r++)
            Yk[(size_t)(gm + r) * DIMC + g2] = f2bf(acc[mt][nt][r] + b);
        } else {
          int g2 = gn - 3072;
          u32 lo = (u32)f2bf(acc[mt][nt][0] + b) | ((u32)f2bf(acc[mt][nt][1] + b) << 16);
          u32 hi = (u32)f2bf(acc[mt][nt][2] + b) | ((u32)f2bf(acc[mt][nt][3] + b) << 16);
          uint2 pk; pk.x = lo; pk.y = hi;
          *(uint2*)(Vt + (size_t)g2 * S_PAD + gm) = pk;
        }
      }
    }
  } else {
    const int fl = *flagp;
    #pragma unroll
    for (int nt = 0; nt < 4; nt++) {
      int gn = gn0 + nt * 16 + l15;
      float b = canon[C_BO + gn];
      #pragma unroll
      for (int mt = 0; mt < 4; mt++) {
        int gm = gm0 + mt * 16 + l4 * 4;
        #pragma unroll
        for (int r = 0; r < 4; r++) {
          int gr = gm + r;
          if (gr < S_LEN) {
            float v = acc[mt][nt][r] + b;
            if (fl) ((float*)Out)[(size_t)gr * DIMC + gn] = v;
            else    ((u16*)Out)[(size_t)gr * DIMC + gn] = f2bf(v);
          }
        }
      }
    }
  }
}

// ---------------- fused RMSNorm + RoPE, wave-per-row ----------------
__global__ void norm_rope(const u16* __restrict__ Yq, const u16* __restrict__ Yk,
                          const float* __restrict__ canon, u16* __restrict__ Qh,
                          u16* __restrict__ Kh) {
  const int tid = threadIdx.x, wave = tid >> 6, lane = tid & 63;
  const int s = blockIdx.x * 4 + wave;
  const int isq = (blockIdx.y == 0);
  const u16* Y = isq ? Yq : Yk;
  const float* g = canon + (isq ? C_GQ : C_GK);
  u16* Oh = isq ? Qh : Kh;
  const float sc = isq ? (0.08838834764831845f * 1.4426950408889634f) : 1.0f;

  const u32* yrow = (const u32*)Y + (size_t)s * 768;
  float xr[12], xi[12];
  float ss = 0.f;
  #pragma unroll
  for (int i = 0; i < 12; i++) {
    u32 d = yrow[lane + 64 * i];
    float a = bf2f((u16)(d & 0xffff));
    float b = bf2f((u16)(d >> 16));
    xr[i] = a; xi[i] = b;
    ss += a * a + b * b;
  }
  #pragma unroll
  for (int dd = 1; dd < 64; dd <<= 1) ss += __shfl_xor(ss, dd, 64);
  float rms = rsqrtf(ss * (1.f / 1536.f) + 1e-6f);

  int f_ = s / FRAME, hh = (s % FRAME) / 28, ww = s % 28;
  const float* fr = canon + C_FR;
  float a = (lane < 22) ? fr[f_ * 64 + lane]
          : (lane < 43) ? fr[hh * 64 + lane]
                        : fr[ww * 64 + lane];
  float si, co;
  __sincosf(a, &si, &co);

  const float2* g2 = (const float2*)g;
  #pragma unroll
  for (int i = 0; i < 12; i++) {
    int p = lane + 64 * i;
    float2 gg = g2[p];
    float r  = xr[i] * rms * gg.x;
    float im = xi[i] * rms * gg.y;
    u32 pk = (u32)f2bf((r * co - im * si) * sc) | ((u32)f2bf((r * si + im * co) * sc) << 16);
    ((u32*)Oh)[((size_t)i * S_LEN + s) * 64 + lane] = pk;
  }
}

// ---------------- flash attention v6: key-half split, one tile in flight ----------------
// 4 waves = (kh, m): kh = key-half of the current 64-key tile, m = q-half (32 q, ct=2).
// One 32 KB swizzled KV tile staged per iter by all 4 waves; LDS 48 KB -> 3 blocks/CU.
// Fixed-max exp2 softmax (pure sums); kh-halves merge once at the end via reused sKV.
__launch_bounds__(256, 3)
__global__ void attn_v6(const u16* __restrict__ Qh, const u16* __restrict__ Kh,
                        const u16* __restrict__ Vt, u16* __restrict__ Ab) {
  const int tid = threadIdx.x, wave = tid >> 6, lane = tid & 63;
  const int l15 = lane & 15, l4 = lane >> 4;
  const int kh = wave >> 1, m = wave & 1;
  const int h = blockIdx.x % 12;
  const int qb = 62 - (blockIdx.x / 12);
  const int q0 = qb * 64;
  const int nkv = (q0 / FRAME + 1) * 7;
  __shared__ u16 sKV[16384];                 // sK = [0,8192), sV = [8192,16384)
  __shared__ u16 sP[8][512];                 // per (wave,ct) P^T in B-frag order
  u16* sK = sKV;
  u16* sV = sKV + 8192;

  // per-lane swizzled global source offsets (v3-verified formulas)
  int koff[4], voff[4];
  #pragma unroll
  for (int i = 0; i < 4; i++) {
    int s = (wave * 4 + i) * 64 + lane;
    int r = s >> 4, c = (s & 15) ^ (r & 15);
    koff[i] = r * HD + c * 8;
    int rv = s >> 3, cv = (s & 7) ^ (rv & 7);
    voff[i] = rv * S_PAD + cv * 8;
  }

  bf16x8 qf[4][2];
  #pragma unroll
  for (int ct = 0; ct < 2; ct++) {
    const u16* qp = Qh + ((size_t)h * S_LEN + q0 + m * 32 + ct * 16 + l15) * HD + l4 * 8;
    #pragma unroll
    for (int ks = 0; ks < 4; ks++) qf[ks][ct] = *(const bf16x8*)(qp + ks * 32);
  }
  f32x4 o[8][2];
  #pragma unroll
  for (int i = 0; i < 8; i++)
    #pragma unroll
    for (int ct = 0; ct < 2; ct++) o[i][ct] = (f32x4){0.f, 0.f, 0.f, 0.f};
  float l_i[2] = {0.f, 0.f};

  const u16* kb0 = Kh + (size_t)h * S_LEN * HD;
  const u16* vb0 = Vt + (size_t)h * HD * S_PAD;

  for (int t = 0; t < nkv; ++t) {
    __syncthreads();   // prior-tile readers done
    {
      const u16* kb = kb0 + (size_t)t * 64 * HD;
      const u16* vb = vb0 + t * 64;
      #pragma unroll
      for (int i = 0; i < 4; i++) {
        gld_lds16(kb + koff[i], (char*)sK + (wave * 4 + i) * 1024);
        gld_lds16(vb + voff[i], (char*)sV + (wave * 4 + i) * 1024);
      }
    }
    __syncthreads();   // staging visible

    // S^T (this wave's 32 keys x 32 q) = K-half . Q^T
    f32x4 sT[2][2];
    #pragma unroll
    for (int nt = 0; nt < 2; nt++)
      #pragma unroll
      for (int ct = 0; ct < 2; ct++) sT[nt][ct] = (f32x4){0.f, 0.f, 0.f, 0.f};
    #pragma unroll
    for (int ks = 0; ks < 4; ks++) {
      bf16x8 kf[2];
      #pragma unroll
      for (int nt = 0; nt < 2; nt++)
        kf[nt] = *(const bf16x8*)(sK + (kh * 32 + nt * 16 + l15) * HD + (((ks * 4 + l4) ^ l15) * 8));
      #pragma unroll
      for (int nt = 0; nt < 2; nt++)
        #pragma unroll
        for (int ct = 0; ct < 2; ct++)
          sT[nt][ct] = mfma16(kf[nt], qf[ks][ct], sT[nt][ct]);
    }

    // fixed-max softmax: p = 2^s, pure accumulation (l xor-reduce deferred to end)
    #pragma unroll
    for (int ct = 0; ct < 2; ct++) {
      float rs = 0.f;
      #pragma unroll
      for (int nt = 0; nt < 2; nt++)
        #pragma unroll
        for (int r = 0; r < 4; r++) {
          float p = __builtin_amdgcn_exp2f(sT[nt][ct][r]);
          sT[nt][ct][r] = p; rs += p;
        }
      l_i[ct] += rs;
      u16* pw = sP[wave * 2 + ct];
      #pragma unroll
      for (int nt = 0; nt < 2; nt++) {
        u32 lo = (u32)f2bf(sT[nt][ct][0]) | ((u32)f2bf(sT[nt][ct][1]) << 16);
        u32 hi = (u32)f2bf(sT[nt][ct][2]) | ((u32)f2bf(sT[nt][ct][3]) << 16);
        u32 off = (u32)((nt * 2 + (l4 >> 1)) * 128 + l15 * 8 + (l4 & 1) * 4);
        uint2 pk; pk.x = lo; pk.y = hi;
        *(uint2*)(pw + off) = pk;
      }
    }

    // O^T += V^T[:, kh-half] . P^T  (one K=32 step)
    bf16x8 pb[2];
    #pragma unroll
    for (int ct = 0; ct < 2; ct++)
      pb[ct] = *(const bf16x8*)(sP[wave * 2 + ct] + lane * 8);
    #pragma unroll
    for (int vt = 0; vt < 8; vt++) {
      bf16x8 vf = *(const bf16x8*)(sV + (vt * 16 + l15) * 64 + (((kh * 4 + l4) ^ (l15 & 7)) * 8));
      #pragma unroll
      for (int ct = 0; ct < 2; ct++)
        o[vt][ct] = mfma16(vf, pb[ct], o[vt][ct]);
    }
  }

  // finish per-wave l (reduce over l4 key-groups)
  #pragma unroll
  for (int ct = 0; ct < 2; ct++) {
    l_i[ct] += __shfl_xor(l_i[ct], 16, 64);
    l_i[ct] += __shfl_xor(l_i[ct], 32, 64);
  }
  __syncthreads();                      // all compute done; sKV/sP reusable as merge buffers
  float* mb = (float*)sKV;              // 32 KB: [(m*2+ct)*8+vt][lane] f32x4
  float* lb = (float*)sP;               // l exchange
  if (kh == 1) {
    #pragma unroll
    for (int ct = 0; ct < 2; ct++) {
      #pragma unroll
      for (int vt = 0; vt < 8; vt++)
        *(f32x4*)(mb + ((((m * 2 + ct) * 8 + vt) * 64) + lane) * 4) = o[vt][ct];
      lb[(m * 2 + ct) * 64 + lane] = l_i[ct];
    }
  }
  __syncthreads();
  if (kh == 0) {
    #pragma unroll
    for (int ct = 0; ct < 2; ct++) {
      float l = l_i[ct] + lb[(m * 2 + ct) * 64 + lane];
      float inv = 1.f / l;
      const size_t orow = (size_t)(q0 + m * 32 + ct * 16 + l15) * DIMC + (size_t)h * HD;
      #pragma unroll
      for (int vt = 0; vt < 8; vt++) {
        f32x4 op = *(const f32x4*)(mb + ((((m * 2 + ct) * 8 + vt) * 64) + lane) * 4);
        float o0 = (o[vt][ct][0] + op[0]) * inv;
        float o1 = (o[vt][ct][1] + op[1]) * inv;
        float o2 = (o[vt][ct][2] + op[2]) * inv;
        float o3 = (o[vt][ct][3] + op[3]) * inv;
        u32 lo = (u32)f2bf(o0) | ((u32)f2bf(o1) << 16);
        u32 hi = (u32)f2bf(o2) | ((u32)f2bf(o3) << 16);
        uint2 pk; pk.x = lo; pk.y = hi;
        *(uint2*)(Ab + orow + vt * 16 + l4 * 4) = pk;
      }
    }
  }
}

extern "C" void kernel_launch(void* const* d_in, const int* in_sizes, int n_in,
                              void* d_out, int out_size, void* d_ws, size_t ws_size,
                              hipStream_t stream) {
  if (ws_size < WS_NEED) return;
  char* ws = (char*)d_ws;
  int*   flag  = (int*)(ws + OFF_FLAG);
  float* canon = (float*)(ws + OFF_CANON);
  u16* xb    = (u16*)(ws + OFF_XB);
  u16* wqkvt = (u16*)(ws + OFF_WT);
  u16* wot   = (u16*)(ws + OFF_WOT);
  u16* yq    = (u16*)(ws + OFF_YQ);
  u16* yk    = (u16*)(ws + OFF_YK);
  u16* vt    = (u16*)(ws + OFF_VT);
  u16* qh    = (u16*)(ws + OFF_QH);
  u16* kh    = (u16*)(ws + OFF_KH);
  u16* ab    = (u16*)(ws + OFF_AT);

  const void* x  = d_in[0];
  const void* fr = d_in[3];
  const void* Wq = d_in[4];  const void* bq = d_in[5];
  const void* Wk = d_in[6];  const void* bk = d_in[7];
  const void* Wv = d_in[8];  const void* bv = d_in[9];
  const void* Wo = d_in[10]; const void* bo = d_in[11];
  const void* gq = d_in[12]; const void* gk = d_in[13];

  detect_dtype<<<1, 256, 0, stream>>>((const u16*)x, flag);
  prep_small<<<292, 256, 0, stream>>>(bq, bk, bv, bo, gq, gk, fr, canon, flag);
  convert_x<<<3072, 256, 0, stream>>>(x, xb, flag);
  transpose_w<<<dim3(48, 48, 4), dim3(32, 8), 0, stream>>>(Wq, Wk, Wv, Wo, wqkvt, wot, flag);
  gemm_bt<0><<<dim3(36, 32), 256, 0, stream>>>(xb, wqkvt, canon, yq, yk, vt, nullptr, flag);
  norm_rope<<<dim3(1008, 2), 256, 0, stream>>>(yq, yk, canon, qh, kh);
  attn_v6<<<756, 256, 0, stream>>>(qh, kh, vt, ab);
  gemm_bt<1><<<dim3(12, 32), 256, 0, stream>>>(ab, wot, canon, nullptr, nullptr, nullptr, d_out, flag);
}

// Round 8
// 346.814 us; speedup vs baseline: 1.0429x; 1.0429x over previous
//
#include <hip/hip_runtime.h>
#include <stdint.h>

typedef unsigned short u16;
typedef unsigned int u32;
typedef __attribute__((ext_vector_type(8))) short bf16x8;
typedef __attribute__((ext_vector_type(4))) float f32x4;

#define S_LEN 4032
#define S_PAD 4096
#define DIMC  1536
#define HD    128
#define FRAME 448

static const size_t OFF_FLAG  = 0;
static const size_t OFF_CANON = 256;
static const size_t OFF_XB    = 524288;
static const size_t OFF_WT    = OFF_XB  + 12582912;
static const size_t OFF_WOT   = OFF_WT  + 14155776;
static const size_t OFF_YQ    = OFF_WOT + 4718592;
static const size_t OFF_YK    = OFF_YQ  + 12582912;
static const size_t OFF_VT    = OFF_YK  + 12582912;
static const size_t OFF_QH    = OFF_VT  + 12582912;
static const size_t OFF_KH    = OFF_QH  + 12386304;
static const size_t OFF_AT    = OFF_KH  + 12386304;
static const size_t WS_NEED   = OFF_AT  + 12582912;

#define C_BQ 0
#define C_BO 4608
#define C_GQ 6144
#define C_GK 7680
#define C_FR 9216
#define C_TOT 74752

__device__ __forceinline__ u16 f2bf(float f) {
  union { float f; u32 u; } v; v.f = f;
  u32 u = v.u;
  u32 r = (u + 0x7fffu + ((u >> 16) & 1u)) >> 16;
  return (u16)r;
}
__device__ __forceinline__ float bf2f(u16 h) {
  union { float f; u32 u; } v; v.u = ((u32)h) << 16;
  return v.f;
}

__device__ __forceinline__ void gld_lds16(const void* g, void* l) {
  __builtin_amdgcn_global_load_lds(
      (const __attribute__((address_space(1))) void*)(uintptr_t)g,
      (__attribute__((address_space(3))) void*)(u32)(uintptr_t)l,
      16, 0, 0);
}

__device__ __forceinline__ f32x4 mfma16(bf16x8 a, bf16x8 b, f32x4 c) {
  return __builtin_amdgcn_mfma_f32_16x16x32_bf16(a, b, c, 0, 0, 0);
}

// ---------------- dtype detection ----------------
__global__ void detect_dtype(const u16* __restrict__ x, int* __restrict__ flag) {
  __shared__ int cnt;
  if (threadIdx.x == 0) cnt = 0;
  __syncthreads();
  int e = (x[2 * threadIdx.x] >> 7) & 0xff;
  if (e > 150) atomicAdd(&cnt, 1);
  __syncthreads();
  if (threadIdx.x == 0) *flag = (cnt >= 8) ? 1 : 0;
}

// ---------------- small tensors -> canonical fp32 ----------------
__global__ void prep_small(const void* bq, const void* bk, const void* bv, const void* bo,
                           const void* gq, const void* gk, const void* fr,
                           float* __restrict__ canon, const int* __restrict__ flagp) {
  int fl = *flagp;
  for (int i = blockIdx.x * 256 + threadIdx.x; i < C_TOT; i += gridDim.x * 256) {
    const void* src; int j;
    if      (i < 1536) { src = bq; j = i; }
    else if (i < 3072) { src = bk; j = i - 1536; }
    else if (i < 4608) { src = bv; j = i - 3072; }
    else if (i < 6144) { src = bo; j = i - 4608; }
    else if (i < 7680) { src = gq; j = i - 6144; }
    else if (i < 9216) { src = gk; j = i - 7680; }
    else               { src = fr; j = i - 9216; }
    canon[i] = fl ? ((const float*)src)[j] : bf2f(((const u16*)src)[j]);
  }
}

// ---------------- x -> bf16, pad rows to 4096 ----------------
__global__ void convert_x(const void* __restrict__ xin, u16* __restrict__ xb,
                          const int* __restrict__ flagp) {
  int fl = *flagp;
  int i = blockIdx.x * 256 + threadIdx.x;
  if (i >= (S_PAD * DIMC) / 8) return;
  size_t base = (size_t)i * 8;
  int row = (int)(base / DIMC);
  union { u16 h[8]; uint4 v; } u;
  if (row < S_LEN) {
    if (fl) {
      const float* xf = (const float*)xin + base;
      #pragma unroll
      for (int j = 0; j < 8; j++) u.h[j] = f2bf(xf[j]);
    } else {
      const u16* xh = (const u16*)xin + base;
      #pragma unroll
      for (int j = 0; j < 8; j++) u.h[j] = xh[j];
    }
  } else {
    #pragma unroll
    for (int j = 0; j < 8; j++) u.h[j] = 0;
  }
  ((uint4*)xb)[i] = u.v;
}

// ---------------- W (K x N) -> Wt (N x K) bf16 ----------------
__global__ void transpose_w(const void* Wq, const void* Wk, const void* Wv, const void* Wo,
                            u16* __restrict__ wqkvt, u16* __restrict__ wot,
                            const int* __restrict__ flagp) {
  int fl = *flagp;
  int z = blockIdx.z;
  const void* W = (z == 0) ? Wq : (z == 1) ? Wk : (z == 2) ? Wv : Wo;
  u16* dst = (z < 3) ? (wqkvt + (size_t)z * DIMC * DIMC) : wot;
  __shared__ float tile[32][33];
  int tx = threadIdx.x, ty = threadIdx.y;
  int c = blockIdx.x * 32 + tx;
  #pragma unroll
  for (int i = 0; i < 4; i++) {
    int r = blockIdx.y * 32 + ty + i * 8;
    float v = fl ? ((const float*)W)[(size_t)r * DIMC + c]
                 : bf2f(((const u16*)W)[(size_t)r * DIMC + c]);
    tile[ty + i * 8][tx] = v;
  }
  __syncthreads();
  int k = blockIdx.y * 32 + tx;
  #pragma unroll
  for (int i = 0; i < 4; i++) {
    int n = blockIdx.x * 32 + ty + i * 8;
    dst[(size_t)n * DIMC + k] = f2bf(tile[tx][ty + i * 8]);
  }
}

// ---------------- GEMM: C(MxN) = A(MxK) @ Bt(NxK)^T + bias ----------------
// n-fast 2D grid + zero-conflict XOR swizzle + 4 blocks/CU (R7-verified).
template <int MODE>
__launch_bounds__(256, 4)
__global__ void gemm_bt(const u16* __restrict__ A, const u16* __restrict__ Bt,
                        const float* __restrict__ canon,
                        u16* __restrict__ Yq, u16* __restrict__ Yk, u16* __restrict__ Vt,
                        void* __restrict__ Out, const int* __restrict__ flagp) {
  const int bm0 = blockIdx.y * 128, bn0 = blockIdx.x * 128;
  const int tid = threadIdx.x, wave = tid >> 6, lane = tid & 63;
  const int wm = wave >> 1, wn = wave & 1;
  const int l15 = lane & 15, l4 = lane >> 4;
  __shared__ u16 sA[128 * 64];
  __shared__ u16 sB[128 * 64];
  f32x4 acc[4][4];
  #pragma unroll
  for (int i = 0; i < 4; i++)
    #pragma unroll
    for (int j = 0; j < 4; j++) acc[i][j] = (f32x4){0.f, 0.f, 0.f, 0.f};

  const int swc = ((lane & 7) ^ (lane >> 3)) * 8;
  const u16* Ab = A  + (size_t)(bm0 + (lane >> 3)) * DIMC + swc;
  const u16* Bb = Bt + (size_t)(bn0 + (lane >> 3)) * DIMC + swc;

  for (int kt = 0; kt < DIMC; kt += 64) {
    __syncthreads();
    #pragma unroll
    for (int c = 0; c < 4; c++) {
      int g = wave * 4 + c;
      gld_lds16(Ab + (size_t)g * 8 * DIMC + kt, (char*)sA + g * 1024);
      gld_lds16(Bb + (size_t)g * 8 * DIMC + kt, (char*)sB + g * 1024);
    }
    __syncthreads();
    #pragma unroll
    for (int ks = 0; ks < 2; ks++) {
      bf16x8 av[4], bvv[4];
      #pragma unroll
      for (int mt = 0; mt < 4; mt++)
        av[mt]  = *(const bf16x8*)(sA + (wm * 64 + mt * 16 + l15) * 64 +
                                   (((ks * 4 + l4) ^ (l15 & 7)) * 8));
      #pragma unroll
      for (int nt = 0; nt < 4; nt++)
        bvv[nt] = *(const bf16x8*)(sB + (wn * 64 + nt * 16 + l15) * 64 +
                                   (((ks * 4 + l4) ^ (l15 & 7)) * 8));
      #pragma unroll
      for (int mt = 0; mt < 4; mt++)
        #pragma unroll
        for (int nt = 0; nt < 4; nt++)
          acc[mt][nt] = mfma16(av[mt], bvv[nt], acc[mt][nt]);
    }
  }

  const int gm0 = bm0 + wm * 64;
  const int gn0 = bn0 + wn * 64;
  if (MODE == 0) {
    #pragma unroll
    for (int nt = 0; nt < 4; nt++) {
      int gn = gn0 + nt * 16 + l15;
      float b = canon[C_BQ + gn];
      #pragma unroll
      for (int mt = 0; mt < 4; mt++) {
        int gm = gm0 + mt * 16 + l4 * 4;
        if (gn < 1536) {
          #pragma unroll
          for (int r = 0; r < 4; r++)
            Yq[(size_t)(gm + r) * DIMC + gn] = f2bf(acc[mt][nt][r] + b);
        } else if (gn < 3072) {
          int g2 = gn - 1536;
          #pragma unroll
          for (int r = 0; r < 4; r++)
            Yk[(size_t)(gm + r) * DIMC + g2] = f2bf(acc[mt][nt][r] + b);
        } else {
          int g2 = gn - 3072;
          u32 lo = (u32)f2bf(acc[mt][nt][0] + b) | ((u32)f2bf(acc[mt][nt][1] + b) << 16);
          u32 hi = (u32)f2bf(acc[mt][nt][2] + b) | ((u32)f2bf(acc[mt][nt][3] + b) << 16);
          uint2 pk; pk.x = lo; pk.y = hi;
          *(uint2*)(Vt + (size_t)g2 * S_PAD + gm) = pk;
        }
      }
    }
  } else {
    const int fl = *flagp;
    #pragma unroll
    for (int nt = 0; nt < 4; nt++) {
      int gn = gn0 + nt * 16 + l15;
      float b = canon[C_BO + gn];
      #pragma unroll
      for (int mt = 0; mt < 4; mt++) {
        int gm = gm0 + mt * 16 + l4 * 4;
        #pragma unroll
        for (int r = 0; r < 4; r++) {
          int gr = gm + r;
          if (gr < S_LEN) {
            float v = acc[mt][nt][r] + b;
            if (fl) ((float*)Out)[(size_t)gr * DIMC + gn] = v;
            else    ((u16*)Out)[(size_t)gr * DIMC + gn] = f2bf(v);
          }
        }
      }
    }
  }
}

// ---------------- fused RMSNorm + RoPE, wave-per-row ----------------
__global__ void norm_rope(const u16* __restrict__ Yq, const u16* __restrict__ Yk,
                          const float* __restrict__ canon, u16* __restrict__ Qh,
                          u16* __restrict__ Kh) {
  const int tid = threadIdx.x, wave = tid >> 6, lane = tid & 63;
  const int s = blockIdx.x * 4 + wave;
  const int isq = (blockIdx.y == 0);
  const u16* Y = isq ? Yq : Yk;
  const float* g = canon + (isq ? C_GQ : C_GK);
  u16* Oh = isq ? Qh : Kh;
  const float sc = isq ? (0.08838834764831845f * 1.4426950408889634f) : 1.0f;

  const u32* yrow = (const u32*)Y + (size_t)s * 768;
  float xr[12], xi[12];
  float ss = 0.f;
  #pragma unroll
  for (int i = 0; i < 12; i++) {
    u32 d = yrow[lane + 64 * i];
    float a = bf2f((u16)(d & 0xffff));
    float b = bf2f((u16)(d >> 16));
    xr[i] = a; xi[i] = b;
    ss += a * a + b * b;
  }
  #pragma unroll
  for (int dd = 1; dd < 64; dd <<= 1) ss += __shfl_xor(ss, dd, 64);
  float rms = rsqrtf(ss * (1.f / 1536.f) + 1e-6f);

  int f_ = s / FRAME, hh = (s % FRAME) / 28, ww = s % 28;
  const float* fr = canon + C_FR;
  float a = (lane < 22) ? fr[f_ * 64 + lane]
          : (lane < 43) ? fr[hh * 64 + lane]
                        : fr[ww * 64 + lane];
  float si, co;
  __sincosf(a, &si, &co);

  const float2* g2 = (const float2*)g;
  #pragma unroll
  for (int i = 0; i < 12; i++) {
    int p = lane + 64 * i;
    float2 gg = g2[p];
    float r  = xr[i] * rms * gg.x;
    float im = xi[i] * rms * gg.y;
    u32 pk = (u32)f2bf((r * co - im * si) * sc) | ((u32)f2bf((r * si + im * co) * sc) << 16);
    ((u32*)Oh)[((size_t)i * S_LEN + s) * 64 + lane] = pk;
  }
}

// ---------------- flash attention v5 (R5/R6 winner, restored verbatim) ----------------
__launch_bounds__(256, 2)
__global__ void attn_v5(const u16* __restrict__ Qh, const u16* __restrict__ Kh,
                        const u16* __restrict__ Vt, u16* __restrict__ Ab) {
  const int tid = threadIdx.x, wave = tid >> 6, lane = tid & 63;
  const int l15 = lane & 15, l4 = lane >> 4;
  const int pair = wave >> 1, m = wave & 1;
  const int h = blockIdx.x % 12;
  const int qb = 62 - (blockIdx.x / 12);
  const int q0 = qb * 64;
  const int nkv = (q0 / FRAME + 1) * 7;
  __shared__ u16 sK[2][8192];
  __shared__ u16 sV[2][8192];
  __shared__ u16 sP[8][1024];

  int koff[8], voff[8];
  #pragma unroll
  for (int i = 0; i < 8; i++) {
    int c = i * 128 + m * 64 + lane;
    int r = c >> 4, cc = (c & 15) ^ (r & 15);
    koff[i] = r * HD + cc * 8;
    int rv = c >> 3, cv = (c & 7) ^ (rv & 7);
    voff[i] = rv * S_PAD + cv * 8;
  }

  bf16x8 qf[4][2];
  #pragma unroll
  for (int ct = 0; ct < 2; ct++) {
    const u16* qp = Qh + ((size_t)h * S_LEN + q0 + m * 32 + ct * 16 + l15) * HD + l4 * 8;
    #pragma unroll
    for (int ks = 0; ks < 4; ks++) qf[ks][ct] = *(const bf16x8*)(qp + ks * 32);
  }
  f32x4 o[8][2];
  #pragma unroll
  for (int i = 0; i < 8; i++)
    #pragma unroll
    for (int ct = 0; ct < 2; ct++) o[i][ct] = (f32x4){0.f, 0.f, 0.f, 0.f};
  float l_i[2] = {0.f, 0.f};

  const u16* kb0 = Kh + (size_t)h * S_LEN * HD;
  const u16* vb0 = Vt + (size_t)h * HD * S_PAD;
  const int niter = (nkv + 1) >> 1;

  for (int it = 0; it < niter; ++it) {
    const int t = it * 2 + pair;
    const bool active = (t < nkv);
    __syncthreads();
    if (active) {
      const u16* kb = kb0 + (size_t)t * 64 * HD;
      const u16* vb = vb0 + t * 64;
      #pragma unroll
      for (int i = 0; i < 8; i++) {
        gld_lds16(kb + koff[i], (char*)sK[pair] + i * 2048 + m * 1024);
        gld_lds16(vb + voff[i], (char*)sV[pair] + i * 2048 + m * 1024);
      }
    }
    __syncthreads();
    if (!active) continue;

    f32x4 sT[4][2];
    #pragma unroll
    for (int nt = 0; nt < 4; nt++)
      #pragma unroll
      for (int ct = 0; ct < 2; ct++) sT[nt][ct] = (f32x4){0.f, 0.f, 0.f, 0.f};
    #pragma unroll
    for (int ks = 0; ks < 4; ks++) {
      bf16x8 kf[4];
      #pragma unroll
      for (int nt = 0; nt < 4; nt++)
        kf[nt] = *(const bf16x8*)(sK[pair] + (nt * 16 + l15) * HD + (((ks * 4 + l4) ^ l15) * 8));
      #pragma unroll
      for (int nt = 0; nt < 4; nt++)
        #pragma unroll
        for (int ct = 0; ct < 2; ct++)
          sT[nt][ct] = mfma16(kf[nt], qf[ks][ct], sT[nt][ct]);
    }

    #pragma unroll
    for (int ct = 0; ct < 2; ct++) {
      float rs = 0.f;
      #pragma unroll
      for (int nt = 0; nt < 4; nt++)
        #pragma unroll
        for (int r = 0; r < 4; r++) {
          float p = __builtin_amdgcn_exp2f(sT[nt][ct][r]);
          sT[nt][ct][r] = p; rs += p;
        }
      l_i[ct] += rs;
      u16* pw = sP[wave * 2 + ct];
      #pragma unroll
      for (int nt = 0; nt < 4; nt++) {
        u32 lo = (u32)f2bf(sT[nt][ct][0]) | ((u32)f2bf(sT[nt][ct][1]) << 16);
        u32 hi = (u32)f2bf(sT[nt][ct][2]) | ((u32)f2bf(sT[nt][ct][3]) << 16);
        u32 off = (u32)((nt >> 1) * 512 + ((nt & 1) * 2 + (l4 >> 1)) * 128 + l15 * 8 + (l4 & 1) * 4);
        uint2 pk; pk.x = lo; pk.y = hi;
        *(uint2*)(pw + off) = pk;
      }
    }

    #pragma unroll
    for (int ks2 = 0; ks2 < 2; ks2++) {
      bf16x8 pb[2];
      #pragma unroll
      for (int ct = 0; ct < 2; ct++)
        pb[ct] = *(const bf16x8*)(sP[wave * 2 + ct] + ks2 * 512 + lane * 8);
      #pragma unroll
      for (int vt = 0; vt < 8; vt++) {
        bf16x8 vf = *(const bf16x8*)(sV[pair] + (vt * 16 + l15) * 64 + (((ks2 * 4 + l4) ^ (l15 & 7)) * 8));
        #pragma unroll
        for (int ct = 0; ct < 2; ct++)
          o[vt][ct] = mfma16(vf, pb[ct], o[vt][ct]);
      }
    }
  }

  #pragma unroll
  for (int ct = 0; ct < 2; ct++) {
    l_i[ct] += __shfl_xor(l_i[ct], 16, 64);
    l_i[ct] += __shfl_xor(l_i[ct], 32, 64);
  }
  __syncthreads();
  float* mb = (float*)sK;
  float* lb = (float*)sP;
  if (pair == 1) {
    #pragma unroll
    for (int ct = 0; ct < 2; ct++) {
      #pragma unroll
      for (int vt = 0; vt < 8; vt++)
        *(f32x4*)(mb + m * 4096 + (ct * 8 + vt) * 256 + lane * 4) = o[vt][ct];
      lb[m * 128 + ct * 64 + lane] = l_i[ct];
    }
  }
  __syncthreads();
  if (pair == 0) {
    #pragma unroll
    for (int ct = 0; ct < 2; ct++) {
      float l = l_i[ct] + lb[m * 128 + ct * 64 + lane];
      float inv = 1.f / l;
      const size_t orow = (size_t)(q0 + m * 32 + ct * 16 + l15) * DIMC + (size_t)h * HD;
      #pragma unroll
      for (int vt = 0; vt < 8; vt++) {
        f32x4 op = *(const f32x4*)(mb + m * 4096 + (ct * 8 + vt) * 256 + lane * 4);
        float o0 = (o[vt][ct][0] + op[0]) * inv;
        float o1 = (o[vt][ct][1] + op[1]) * inv;
        float o2 = (o[vt][ct][2] + op[2]) * inv;
        float o3 = (o[vt][ct][3] + op[3]) * inv;
        u32 lo = (u32)f2bf(o0) | ((u32)f2bf(o1) << 16);
        u32 hi = (u32)f2bf(o2) | ((u32)f2bf(o3) << 16);
        uint2 pk; pk.x = lo; pk.y = hi;
        *(uint2*)(Ab + orow + vt * 16 + l4 * 4) = pk;
      }
    }
  }
}

extern "C" void kernel_launch(void* const* d_in, const int* in_sizes, int n_in,
                              void* d_out, int out_size, void* d_ws, size_t ws_size,
                              hipStream_t stream) {
  if (ws_size < WS_NEED) return;
  char* ws = (char*)d_ws;
  int*   flag  = (int*)(ws + OFF_FLAG);
  float* canon = (float*)(ws + OFF_CANON);
  u16* xb    = (u16*)(ws + OFF_XB);
  u16* wqkvt = (u16*)(ws + OFF_WT);
  u16* wot   = (u16*)(ws + OFF_WOT);
  u16* yq    = (u16*)(ws + OFF_YQ);
  u16* yk    = (u16*)(ws + OFF_YK);
  u16* vt    = (u16*)(ws + OFF_VT);
  u16* qh    = (u16*)(ws + OFF_QH);
  u16* kh    = (u16*)(ws + OFF_KH);
  u16* ab    = (u16*)(ws + OFF_AT);

  const void* x  = d_in[0];
  const void* fr = d_in[3];
  const void* Wq = d_in[4];  const void* bq = d_in[5];
  const void* Wk = d_in[6];  const void* bk = d_in[7];
  const void* Wv = d_in[8];  const void* bv = d_in[9];
  const void* Wo = d_in[10]; const void* bo = d_in[11];
  const void* gq = d_in[12]; const void* gk = d_in[13];

  detect_dtype<<<1, 256, 0, stream>>>((const u16*)x, flag);
  prep_small<<<292, 256, 0, stream>>>(bq, bk, bv, bo, gq, gk, fr, canon, flag);
  convert_x<<<3072, 256, 0, stream>>>(x, xb, flag);
  transpose_w<<<dim3(48, 48, 4), dim3(32, 8), 0, stream>>>(Wq, Wk, Wv, Wo, wqkvt, wot, flag);
  gemm_bt<0><<<dim3(36, 32), 256, 0, stream>>>(xb, wqkvt, canon, yq, yk, vt, nullptr, flag);
  norm_rope<<<dim3(1008, 2), 256, 0, stream>>>(yq, yk, canon, qh, kh);
  attn_v5<<<756, 256, 0, stream>>>(qh, kh, vt, ab);
  gemm_bt<1><<<dim3(12, 32), 256, 0, stream>>>(ab, wot, canon, nullptr, nullptr, nullptr, d_out, flag);
}

// Round 9
// 337.452 us; speedup vs baseline: 1.0718x; 1.0277x over previous
//
#include <hip/hip_runtime.h>
#include <stdint.h>

typedef unsigned short u16;
typedef unsigned int u32;
typedef __attribute__((ext_vector_type(8))) short bf16x8;
typedef __attribute__((ext_vector_type(4))) float f32x4;

#define S_LEN 4032
#define S_PAD 4096
#define DIMC  1536
#define HD    128
#define FRAME 448

static const size_t OFF_FLAG  = 0;
static const size_t OFF_CANON = 256;
static const size_t OFF_XB    = 524288;
static const size_t OFF_WT    = OFF_XB  + 12582912;
static const size_t OFF_WOT   = OFF_WT  + 14155776;
static const size_t OFF_YQ    = OFF_WOT + 4718592;
static const size_t OFF_YK    = OFF_YQ  + 12582912;
static const size_t OFF_VT    = OFF_YK  + 12582912;
static const size_t OFF_QH    = OFF_VT  + 12582912;
static const size_t OFF_KH    = OFF_QH  + 12386304;
static const size_t OFF_AT    = OFF_KH  + 12386304;
static const size_t WS_NEED   = OFF_AT  + 12582912;

#define C_BQ 0
#define C_BO 4608
#define C_GQ 6144
#define C_GK 7680
#define C_FR 9216
#define C_TOT 74752

__device__ __forceinline__ u16 f2bf(float f) {
  union { float f; u32 u; } v; v.f = f;
  u32 u = v.u;
  u32 r = (u + 0x7fffu + ((u >> 16) & 1u)) >> 16;
  return (u16)r;
}
__device__ __forceinline__ float bf2f(u16 h) {
  union { float f; u32 u; } v; v.u = ((u32)h) << 16;
  return v.f;
}

__device__ __forceinline__ void gld_lds16(const void* g, void* l) {
  __builtin_amdgcn_global_load_lds(
      (const __attribute__((address_space(1))) void*)(uintptr_t)g,
      (__attribute__((address_space(3))) void*)(u32)(uintptr_t)l,
      16, 0, 0);
}

__device__ __forceinline__ f32x4 mfma16(bf16x8 a, bf16x8 b, f32x4 c) {
  return __builtin_amdgcn_mfma_f32_16x16x32_bf16(a, b, c, 0, 0, 0);
}

// ---------------- fused preprocessing: detect + transpose_w + convert_x + small ----------------
// Each block detects the input dtype LOCALLY (no cross-block dependency); block 0
// materializes the flag for gemm_bt<1>'s epilogue. blockIdx ranges:
//   [0, 9216)        : W transpose (z = bid/2304, by = (bid%2304)/48, bx = bid%48)
//   [9216, 12288)    : x -> bf16 padded
//   [12288, 12580)   : biases/gains/freqs -> canon fp32
__global__ void prep_all(const void* __restrict__ x,
                         const void* Wq, const void* Wk, const void* Wv, const void* Wo,
                         const void* bq, const void* bk, const void* bv, const void* bo,
                         const void* gq, const void* gk, const void* fr,
                         float* __restrict__ canon, u16* __restrict__ xb,
                         u16* __restrict__ wqkvt, u16* __restrict__ wot,
                         int* __restrict__ flag) {
  __shared__ int cnt;
  __shared__ float tile[32][33];
  const int tid = threadIdx.x;
  if (tid == 0) cnt = 0;
  __syncthreads();
  int e = (((const u16*)x)[2 * tid] >> 7) & 0xff;
  if (e > 150) atomicAdd(&cnt, 1);
  __syncthreads();
  const int fl = (cnt >= 8) ? 1 : 0;   // 1 = fp32 inputs, 0 = bf16
  const int bid = blockIdx.x;
  if (bid == 0 && tid == 0) *flag = fl;

  if (bid < 9216) {
    // ---- W (K x N) -> Wt (N x K) bf16 ----
    const int z = bid / 2304;
    const int rem = bid % 2304;
    const int by = rem / 48, bx = rem % 48;
    const void* W = (z == 0) ? Wq : (z == 1) ? Wk : (z == 2) ? Wv : Wo;
    u16* dst = (z < 3) ? (wqkvt + (size_t)z * DIMC * DIMC) : wot;
    const int tx = tid & 31, ty = tid >> 5;
    const int c = bx * 32 + tx;
    #pragma unroll
    for (int i = 0; i < 4; i++) {
      int r = by * 32 + ty + i * 8;
      float v = fl ? ((const float*)W)[(size_t)r * DIMC + c]
                   : bf2f(((const u16*)W)[(size_t)r * DIMC + c]);
      tile[ty + i * 8][tx] = v;
    }
    __syncthreads();
    const int k = by * 32 + tx;
    #pragma unroll
    for (int i = 0; i < 4; i++) {
      int n = bx * 32 + ty + i * 8;
      dst[(size_t)n * DIMC + k] = f2bf(tile[tx][ty + i * 8]);
    }
  } else if (bid < 12288) {
    // ---- x -> bf16, pad rows to 4096 ----
    int i = (bid - 9216) * 256 + tid;
    if (i < (S_PAD * DIMC) / 8) {
      size_t base = (size_t)i * 8;
      int row = (int)(base / DIMC);
      union { u16 h[8]; uint4 v; } u;
      if (row < S_LEN) {
        if (fl) {
          const float* xf = (const float*)x + base;
          #pragma unroll
          for (int j = 0; j < 8; j++) u.h[j] = f2bf(xf[j]);
        } else {
          const u16* xh = (const u16*)x + base;
          #pragma unroll
          for (int j = 0; j < 8; j++) u.h[j] = xh[j];
        }
      } else {
        #pragma unroll
        for (int j = 0; j < 8; j++) u.h[j] = 0;
      }
      ((uint4*)xb)[i] = u.v;
    }
  } else {
    // ---- small tensors -> canonical fp32 ----
    for (int i = (bid - 12288) * 256 + tid; i < C_TOT; i += 292 * 256) {
      const void* src; int j;
      if      (i < 1536) { src = bq; j = i; }
      else if (i < 3072) { src = bk; j = i - 1536; }
      else if (i < 4608) { src = bv; j = i - 3072; }
      else if (i < 6144) { src = bo; j = i - 4608; }
      else if (i < 7680) { src = gq; j = i - 6144; }
      else if (i < 9216) { src = gk; j = i - 7680; }
      else               { src = fr; j = i - 9216; }
      canon[i] = fl ? ((const float*)src)[j] : bf2f(((const u16*)src)[j]);
    }
  }
}

// ---------------- GEMM: C(MxN) = A(MxK) @ Bt(NxK)^T + bias ----------------
// n-fast 2D grid + zero-conflict XOR swizzle + 4 blocks/CU (R7/R8-verified).
template <int MODE>
__launch_bounds__(256, 4)
__global__ void gemm_bt(const u16* __restrict__ A, const u16* __restrict__ Bt,
                        const float* __restrict__ canon,
                        u16* __restrict__ Yq, u16* __restrict__ Yk, u16* __restrict__ Vt,
                        void* __restrict__ Out, const int* __restrict__ flagp) {
  const int bm0 = blockIdx.y * 128, bn0 = blockIdx.x * 128;
  const int tid = threadIdx.x, wave = tid >> 6, lane = tid & 63;
  const int wm = wave >> 1, wn = wave & 1;
  const int l15 = lane & 15, l4 = lane >> 4;
  __shared__ u16 sA[128 * 64];
  __shared__ u16 sB[128 * 64];
  f32x4 acc[4][4];
  #pragma unroll
  for (int i = 0; i < 4; i++)
    #pragma unroll
    for (int j = 0; j < 4; j++) acc[i][j] = (f32x4){0.f, 0.f, 0.f, 0.f};

  const int swc = ((lane & 7) ^ (lane >> 3)) * 8;
  const u16* Ab = A  + (size_t)(bm0 + (lane >> 3)) * DIMC + swc;
  const u16* Bb = Bt + (size_t)(bn0 + (lane >> 3)) * DIMC + swc;

  for (int kt = 0; kt < DIMC; kt += 64) {
    __syncthreads();
    #pragma unroll
    for (int c = 0; c < 4; c++) {
      int g = wave * 4 + c;
      gld_lds16(Ab + (size_t)g * 8 * DIMC + kt, (char*)sA + g * 1024);
      gld_lds16(Bb + (size_t)g * 8 * DIMC + kt, (char*)sB + g * 1024);
    }
    __syncthreads();
    #pragma unroll
    for (int ks = 0; ks < 2; ks++) {
      bf16x8 av[4], bvv[4];
      #pragma unroll
      for (int mt = 0; mt < 4; mt++)
        av[mt]  = *(const bf16x8*)(sA + (wm * 64 + mt * 16 + l15) * 64 +
                                   (((ks * 4 + l4) ^ (l15 & 7)) * 8));
      #pragma unroll
      for (int nt = 0; nt < 4; nt++)
        bvv[nt] = *(const bf16x8*)(sB + (wn * 64 + nt * 16 + l15) * 64 +
                                   (((ks * 4 + l4) ^ (l15 & 7)) * 8));
      #pragma unroll
      for (int mt = 0; mt < 4; mt++)
        #pragma unroll
        for (int nt = 0; nt < 4; nt++)
          acc[mt][nt] = mfma16(av[mt], bvv[nt], acc[mt][nt]);
    }
  }

  const int gm0 = bm0 + wm * 64;
  const int gn0 = bn0 + wn * 64;
  if (MODE == 0) {
    #pragma unroll
    for (int nt = 0; nt < 4; nt++) {
      int gn = gn0 + nt * 16 + l15;
      float b = canon[C_BQ + gn];
      #pragma unroll
      for (int mt = 0; mt < 4; mt++) {
        int gm = gm0 + mt * 16 + l4 * 4;
        if (gn < 1536) {
          #pragma unroll
          for (int r = 0; r < 4; r++)
            Yq[(size_t)(gm + r) * DIMC + gn] = f2bf(acc[mt][nt][r] + b);
        } else if (gn < 3072) {
          int g2 = gn - 1536;
          #pragma unroll
          for (int r = 0; r < 4; r++)
            Yk[(size_t)(gm + r) * DIMC + g2] = f2bf(acc[mt][nt][r] + b);
        } else {
          int g2 = gn - 3072;
          u32 lo = (u32)f2bf(acc[mt][nt][0] + b) | ((u32)f2bf(acc[mt][nt][1] + b) << 16);
          u32 hi = (u32)f2bf(acc[mt][nt][2] + b) | ((u32)f2bf(acc[mt][nt][3] + b) << 16);
          uint2 pk; pk.x = lo; pk.y = hi;
          *(uint2*)(Vt + (size_t)g2 * S_PAD + gm) = pk;
        }
      }
    }
  } else {
    const int fl = *flagp;
    #pragma unroll
    for (int nt = 0; nt < 4; nt++) {
      int gn = gn0 + nt * 16 + l15;
      float b = canon[C_BO + gn];
      #pragma unroll
      for (int mt = 0; mt < 4; mt++) {
        int gm = gm0 + mt * 16 + l4 * 4;
        #pragma unroll
        for (int r = 0; r < 4; r++) {
          int gr = gm + r;
          if (gr < S_LEN) {
            float v = acc[mt][nt][r] + b;
            if (fl) ((float*)Out)[(size_t)gr * DIMC + gn] = v;
            else    ((u16*)Out)[(size_t)gr * DIMC + gn] = f2bf(v);
          }
        }
      }
    }
  }
}

// ---------------- fused RMSNorm + RoPE, wave-per-row ----------------
__global__ void norm_rope(const u16* __restrict__ Yq, const u16* __restrict__ Yk,
                          const float* __restrict__ canon, u16* __restrict__ Qh,
                          u16* __restrict__ Kh) {
  const int tid = threadIdx.x, wave = tid >> 6, lane = tid & 63;
  const int s = blockIdx.x * 4 + wave;
  const int isq = (blockIdx.y == 0);
  const u16* Y = isq ? Yq : Yk;
  const float* g = canon + (isq ? C_GQ : C_GK);
  u16* Oh = isq ? Qh : Kh;
  const float sc = isq ? (0.08838834764831845f * 1.4426950408889634f) : 1.0f;

  const u32* yrow = (const u32*)Y + (size_t)s * 768;
  float xr[12], xi[12];
  float ss = 0.f;
  #pragma unroll
  for (int i = 0; i < 12; i++) {
    u32 d = yrow[lane + 64 * i];
    float a = bf2f((u16)(d & 0xffff));
    float b = bf2f((u16)(d >> 16));
    xr[i] = a; xi[i] = b;
    ss += a * a + b * b;
  }
  #pragma unroll
  for (int dd = 1; dd < 64; dd <<= 1) ss += __shfl_xor(ss, dd, 64);
  float rms = rsqrtf(ss * (1.f / 1536.f) + 1e-6f);

  int f_ = s / FRAME, hh = (s % FRAME) / 28, ww = s % 28;
  const float* fr = canon + C_FR;
  float a = (lane < 22) ? fr[f_ * 64 + lane]
          : (lane < 43) ? fr[hh * 64 + lane]
                        : fr[ww * 64 + lane];
  float si, co;
  __sincosf(a, &si, &co);

  const float2* g2 = (const float2*)g;
  #pragma unroll
  for (int i = 0; i < 12; i++) {
    int p = lane + 64 * i;
    float2 gg = g2[p];
    float r  = xr[i] * rms * gg.x;
    float im = xi[i] * rms * gg.y;
    u32 pk = (u32)f2bf((r * co - im * si) * sc) | ((u32)f2bf((r * si + im * co) * sc) << 16);
    ((u32*)Oh)[((size_t)i * S_LEN + s) * 64 + lane] = pk;
  }
}

// ---------------- flash attention v5 (R5/R8 winner, unchanged) ----------------
__launch_bounds__(256, 2)
__global__ void attn_v5(const u16* __restrict__ Qh, const u16* __restrict__ Kh,
                        const u16* __restrict__ Vt, u16* __restrict__ Ab) {
  const int tid = threadIdx.x, wave = tid >> 6, lane = tid & 63;
  const int l15 = lane & 15, l4 = lane >> 4;
  const int pair = wave >> 1, m = wave & 1;
  const int h = blockIdx.x % 12;
  const int qb = 62 - (blockIdx.x / 12);
  const int q0 = qb * 64;
  const int nkv = (q0 / FRAME + 1) * 7;
  __shared__ u16 sK[2][8192];
  __shared__ u16 sV[2][8192];
  __shared__ u16 sP[8][1024];

  int koff[8], voff[8];
  #pragma unroll
  for (int i = 0; i < 8; i++) {
    int c = i * 128 + m * 64 + lane;
    int r = c >> 4, cc = (c & 15) ^ (r & 15);
    koff[i] = r * HD + cc * 8;
    int rv = c >> 3, cv = (c & 7) ^ (rv & 7);
    voff[i] = rv * S_PAD + cv * 8;
  }

  bf16x8 qf[4][2];
  #pragma unroll
  for (int ct = 0; ct < 2; ct++) {
    const u16* qp = Qh + ((size_t)h * S_LEN + q0 + m * 32 + ct * 16 + l15) * HD + l4 * 8;
    #pragma unroll
    for (int ks = 0; ks < 4; ks++) qf[ks][ct] = *(const bf16x8*)(qp + ks * 32);
  }
  f32x4 o[8][2];
  #pragma unroll
  for (int i = 0; i < 8; i++)
    #pragma unroll
    for (int ct = 0; ct < 2; ct++) o[i][ct] = (f32x4){0.f, 0.f, 0.f, 0.f};
  float l_i[2] = {0.f, 0.f};

  const u16* kb0 = Kh + (size_t)h * S_LEN * HD;
  const u16* vb0 = Vt + (size_t)h * HD * S_PAD;
  const int niter = (nkv + 1) >> 1;

  for (int it = 0; it < niter; ++it) {
    const int t = it * 2 + pair;
    const bool active = (t < nkv);
    __syncthreads();
    if (active) {
      const u16* kb = kb0 + (size_t)t * 64 * HD;
      const u16* vb = vb0 + t * 64;
      #pragma unroll
      for (int i = 0; i < 8; i++) {
        gld_lds16(kb + koff[i], (char*)sK[pair] + i * 2048 + m * 1024);
        gld_lds16(vb + voff[i], (char*)sV[pair] + i * 2048 + m * 1024);
      }
    }
    __syncthreads();
    if (!active) continue;

    f32x4 sT[4][2];
    #pragma unroll
    for (int nt = 0; nt < 4; nt++)
      #pragma unroll
      for (int ct = 0; ct < 2; ct++) sT[nt][ct] = (f32x4){0.f, 0.f, 0.f, 0.f};
    #pragma unroll
    for (int ks = 0; ks < 4; ks++) {
      bf16x8 kf[4];
      #pragma unroll
      for (int nt = 0; nt < 4; nt++)
        kf[nt] = *(const bf16x8*)(sK[pair] + (nt * 16 + l15) * HD + (((ks * 4 + l4) ^ l15) * 8));
      #pragma unroll
      for (int nt = 0; nt < 4; nt++)
        #pragma unroll
        for (int ct = 0; ct < 2; ct++)
          sT[nt][ct] = mfma16(kf[nt], qf[ks][ct], sT[nt][ct]);
    }

    #pragma unroll
    for (int ct = 0; ct < 2; ct++) {
      float rs = 0.f;
      #pragma unroll
      for (int nt = 0; nt < 4; nt++)
        #pragma unroll
        for (int r = 0; r < 4; r++) {
          float p = __builtin_amdgcn_exp2f(sT[nt][ct][r]);
          sT[nt][ct][r] = p; rs += p;
        }
      l_i[ct] += rs;
      u16* pw = sP[wave * 2 + ct];
      #pragma unroll
      for (int nt = 0; nt < 4; nt++) {
        u32 lo = (u32)f2bf(sT[nt][ct][0]) | ((u32)f2bf(sT[nt][ct][1]) << 16);
        u32 hi = (u32)f2bf(sT[nt][ct][2]) | ((u32)f2bf(sT[nt][ct][3]) << 16);
        u32 off = (u32)((nt >> 1) * 512 + ((nt & 1) * 2 + (l4 >> 1)) * 128 + l15 * 8 + (l4 & 1) * 4);
        uint2 pk; pk.x = lo; pk.y = hi;
        *(uint2*)(pw + off) = pk;
      }
    }

    #pragma unroll
    for (int ks2 = 0; ks2 < 2; ks2++) {
      bf16x8 pb[2];
      #pragma unroll
      for (int ct = 0; ct < 2; ct++)
        pb[ct] = *(const bf16x8*)(sP[wave * 2 + ct] + ks2 * 512 + lane * 8);
      #pragma unroll
      for (int vt = 0; vt < 8; vt++) {
        bf16x8 vf = *(const bf16x8*)(sV[pair] + (vt * 16 + l15) * 64 + (((ks2 * 4 + l4) ^ (l15 & 7)) * 8));
        #pragma unroll
        for (int ct = 0; ct < 2; ct++)
          o[vt][ct] = mfma16(vf, pb[ct], o[vt][ct]);
      }
    }
  }

  #pragma unroll
  for (int ct = 0; ct < 2; ct++) {
    l_i[ct] += __shfl_xor(l_i[ct], 16, 64);
    l_i[ct] += __shfl_xor(l_i[ct], 32, 64);
  }
  __syncthreads();
  float* mb = (float*)sK;
  float* lb = (float*)sP;
  if (pair == 1) {
    #pragma unroll
    for (int ct = 0; ct < 2; ct++) {
      #pragma unroll
      for (int vt = 0; vt < 8; vt++)
        *(f32x4*)(mb + m * 4096 + (ct * 8 + vt) * 256 + lane * 4) = o[vt][ct];
      lb[m * 128 + ct * 64 + lane] = l_i[ct];
    }
  }
  __syncthreads();
  if (pair == 0) {
    #pragma unroll
    for (int ct = 0; ct < 2; ct++) {
      float l = l_i[ct] + lb[m * 128 + ct * 64 + lane];
      float inv = 1.f / l;
      const size_t orow = (size_t)(q0 + m * 32 + ct * 16 + l15) * DIMC + (size_t)h * HD;
      #pragma unroll
      for (int vt = 0; vt < 8; vt++) {
        f32x4 op = *(const f32x4*)(mb + m * 4096 + (ct * 8 + vt) * 256 + lane * 4);
        float o0 = (o[vt][ct][0] + op[0]) * inv;
        float o1 = (o[vt][ct][1] + op[1]) * inv;
        float o2 = (o[vt][ct][2] + op[2]) * inv;
        float o3 = (o[vt][ct][3] + op[3]) * inv;
        u32 lo = (u32)f2bf(o0) | ((u32)f2bf(o1) << 16);
        u32 hi = (u32)f2bf(o2) | ((u32)f2bf(o3) << 16);
        uint2 pk; pk.x = lo; pk.y = hi;
        *(uint2*)(Ab + orow + vt * 16 + l4 * 4) = pk;
      }
    }
  }
}

extern "C" void kernel_launch(void* const* d_in, const int* in_sizes, int n_in,
                              void* d_out, int out_size, void* d_ws, size_t ws_size,
                              hipStream_t stream) {
  if (ws_size < WS_NEED) return;
  char* ws = (char*)d_ws;
  int*   flag  = (int*)(ws + OFF_FLAG);
  float* canon = (float*)(ws + OFF_CANON);
  u16* xb    = (u16*)(ws + OFF_XB);
  u16* wqkvt = (u16*)(ws + OFF_WT);
  u16* wot   = (u16*)(ws + OFF_WOT);
  u16* yq    = (u16*)(ws + OFF_YQ);
  u16* yk    = (u16*)(ws + OFF_YK);
  u16* vt    = (u16*)(ws + OFF_VT);
  u16* qh    = (u16*)(ws + OFF_QH);
  u16* kh    = (u16*)(ws + OFF_KH);
  u16* ab    = (u16*)(ws + OFF_AT);

  const void* x  = d_in[0];
  const void* fr = d_in[3];
  const void* Wq = d_in[4];  const void* bq = d_in[5];
  const void* Wk = d_in[6];  const void* bk = d_in[7];
  const void* Wv = d_in[8];  const void* bv = d_in[9];
  const void* Wo = d_in[10]; const void* bo = d_in[11];
  const void* gq = d_in[12]; const void* gk = d_in[13];

  prep_all<<<12580, 256, 0, stream>>>(x, Wq, Wk, Wv, Wo, bq, bk, bv, bo, gq, gk, fr,
                                      canon, xb, wqkvt, wot, flag);
  gemm_bt<0><<<dim3(36, 32), 256, 0, stream>>>(xb, wqkvt, canon, yq, yk, vt, nullptr, flag);
  norm_rope<<<dim3(1008, 2), 256, 0, stream>>>(yq, yk, canon, qh, kh);
  attn_v5<<<756, 256, 0, stream>>>(qh, kh, vt, ab);
  gemm_bt<1><<<dim3(12, 32), 256, 0, stream>>>(ab, wot, canon, nullptr, nullptr, nullptr, d_out, flag);
}